// Round 5
// baseline (199.512 us; speedup 1.0000x reference)
//
#include <hip/hip_runtime.h>

// B=32, C=3, H=W=512 fp32.
// x^gamma -> *wb -> contrast about per-plane mean (clip) -> 3x3 sharpen -> blend -> clip.
// K1: per-(plane,chunk) partial sums of x^g (768 floats in d_ws, no memset/atomics).
// K2: LDS-free fused pointwise+conv: register-rolling 3-row window per wave,
//     cross-lane halo via shuffles, NT b128 stores.
//
// R1: __powf == __ocml_pow_f32 (~100 instr) -> VALU-bound; use v_log/v_exp.
// R2: scalar ds_read conv -> LDS-issue-bound; b128 reads fixed it.
// R4: hipLaunchCooperativeKernel breaks harness graph capture (out never written)
//     -> stay with two stream-ordered launches.
// R5: drop LDS entirely: per-wave 256x16 strip, rolling registers + shuffles.

#define HH 512
#define WW 512
#define NPLANE (HH * WW)
#define NPLANES 96
#define CHUNKS 8
#define ROWS 16                       // output rows per wave-strip

typedef float f4 __attribute__((ext_vector_type(4)));

__device__ __forceinline__ float fpow(float v, float g) {
    return __builtin_amdgcn_exp2f(g * __builtin_amdgcn_logf(v));   // 0^g -> 0 exact
}
__device__ __forceinline__ float tfm(float v, float g, float wbc, float mean, float ct) {
    float p = fpow(v, g) * wbc;
    return __saturatef((p - mean) * ct + mean);
}

// ---------------- Kernel 1: per-(plane,chunk) partial sums of x^g ----------------
__global__ __launch_bounds__(256) void mean_kernel(
    const float* __restrict__ x,
    const float* __restrict__ gamma,
    float* __restrict__ partials)
{
    const int blk   = blockIdx.x;
    const int plane = blk / CHUNKS;
    const float g   = gamma[plane / 3];

    const float4* xp = (const float4*)(x + (size_t)plane * NPLANE)
                       + (size_t)(blk % CHUNKS) * (NPLANE / CHUNKS / 4);
    const int tid = threadIdx.x;

    float acc = 0.f;
    #pragma unroll
    for (int i = 0; i < 32; ++i) {
        float4 v = xp[i * 256 + tid];
        acc += fpow(v.x, g) + fpow(v.y, g) + fpow(v.z, g) + fpow(v.w, g);
    }
    #pragma unroll
    for (int off = 32; off > 0; off >>= 1)
        acc += __shfl_down(acc, off, 64);

    __shared__ float wsum[4];
    if ((tid & 63) == 0) wsum[tid >> 6] = acc;
    __syncthreads();
    if (tid == 0) partials[blk] = wsum[0] + wsum[1] + wsum[2] + wsum[3];
}

// ---------------- Kernel 2: LDS-free fused pointwise + 3x3 sharpen + blend ----------------
// 6144 wave-strips: plane (96) x colHalf (2) x rowBand (32). Each wave: 256 cols
// (4/lane) x 16 output rows. Rolling h(r-2),h(r-1),h(r); halo cols via shuffles,
// strip-edge cols via 2 exec-masked scalar loads; row loads prefetched by 1.
__global__ __launch_bounds__(256) void fuse_kernel(
    const float* __restrict__ x,
    const float* __restrict__ gamma,
    const float* __restrict__ wb,
    const float* __restrict__ contrast,
    const float* __restrict__ sharpen,
    const float* __restrict__ partials,
    float* __restrict__ out)
{
    const int tid  = threadIdx.x;
    const int lane = tid & 63;
    const int wave = tid >> 6;
    const int wg   = blockIdx.x * 4 + wave;      // 0..6143
    const int plane = wg >> 6;
    const int s6    = wg & 63;
    const int base  = (s6 & 1) * 256;            // column half base
    const int y0    = (s6 >> 1) * ROWS;          // output row base

    const int b     = plane / 3;
    const float g   = gamma[b];
    const float wbc = wb[plane];
    const float ct  = contrast[b];
    const float s   = sharpen[b];

    float psum = 0.f;
    const float* pp = partials + plane * CHUNKS;
    #pragma unroll
    for (int i = 0; i < CHUNKS; ++i) psum += pp[i];
    const float mean = psum * wbc * (1.0f / (float)NPLANE);

    const float* xp = x + (size_t)plane * NPLANE;
    float* op       = out + (size_t)plane * NPLANE;
    const int ci    = (base >> 2) + lane;        // f4 index within a row
    const float c1  = 1.0f + 9.0f * s;           // out = clip(c1*center - s*sum9)

    f4 hm2, hm1, mprev, vcur;
    {
        int r0 = y0 - 1;
        vcur = (r0 >= 0) ? ((const f4*)(xp + (size_t)r0 * WW))[ci] : (f4)0.f;
    }

    #pragma unroll
    for (int idx = 0; idx < ROWS + 2; ++idx) {
        const int r  = y0 - 1 + idx;
        const int rn = r + 1;
        f4 vnext = (f4)0.f;
        if (idx < ROWS + 1 && rn < HH)           // prefetch next row
            vnext = ((const f4*)(xp + (size_t)rn * WW))[ci];

        f4 B;
        const bool rv = (r >= 0) & (r < HH);
        if (rv) {
            B.x = tfm(vcur.x, g, wbc, mean, ct);
            B.y = tfm(vcur.y, g, wbc, mean, ct);
            B.z = tfm(vcur.z, g, wbc, mean, ct);
            B.w = tfm(vcur.w, g, wbc, mean, ct);
        } else {
            B = (f4)0.f;
        }

        // strip-edge halo columns (plane edge -> 0)
        float eL = 0.f, eR = 0.f;
        if (rv && lane == 0 && base > 0)
            eL = tfm(xp[(size_t)r * WW + base - 1], g, wbc, mean, ct);
        if (rv && lane == 63 && base + 256 < WW)
            eR = tfm(xp[(size_t)r * WW + base + 256], g, wbc, mean, ct);

        float lo = __shfl_up(B.w, 1);  if (lane == 0)  lo = eL;
        float hi = __shfl_down(B.x, 1); if (lane == 63) hi = eR;

        f4 hr;
        hr.x = lo  + B.x + B.y;
        hr.y = B.x + B.y + B.z;
        hr.z = B.y + B.z + B.w;
        hr.w = B.z + B.w + hi;

        if (idx >= 2) {                          // emit output row r-1
            f4 sum = hm2 + hm1 + hr;
            f4 o;
            o.x = __saturatef(fmaf(c1, mprev.x, -s * sum.x));
            o.y = __saturatef(fmaf(c1, mprev.y, -s * sum.y));
            o.z = __saturatef(fmaf(c1, mprev.z, -s * sum.z));
            o.w = __saturatef(fmaf(c1, mprev.w, -s * sum.w));
            __builtin_nontemporal_store(o, (f4*)(op + (size_t)(r - 1) * WW) + ci);
        }
        hm2 = hm1; hm1 = hr; mprev = B; vcur = vnext;
    }
}

extern "C" void kernel_launch(void* const* d_in, const int* in_sizes, int n_in,
                              void* d_out, int out_size, void* d_ws, size_t ws_size,
                              hipStream_t stream) {
    const float* x        = (const float*)d_in[0];
    const float* gamma    = (const float*)d_in[1];
    const float* wb       = (const float*)d_in[2];
    const float* contrast = (const float*)d_in[3];
    const float* sharpen  = (const float*)d_in[4];
    float* out      = (float*)d_out;
    float* partials = (float*)d_ws;              // 768 floats, fully rewritten each call

    mean_kernel<<<dim3(NPLANES * CHUNKS), 256, 0, stream>>>(x, gamma, partials);
    fuse_kernel<<<dim3(6144 / 4), 256, 0, stream>>>(x, gamma, wb, contrast,
                                                    sharpen, partials, out);
}